// Round 2
// 447.305 us; speedup vs baseline: 1.0765x; 1.0765x over previous
//
#include <hip/hip_runtime.h>
#include <stdint.h>
#include <stddef.h>

// Problem constants
constexpr int B_ = 16, N_ = 8, C_ = 3, H_ = 48, W_ = 48, K_ = 5, NK_ = 4;
constexpr int HW_ = H_ * W_;            // 2304
constexpr int IMGS_ = B_ * N_;          // 128
constexpr int PW_ = W_ + 4;             // 52 (padded width)
constexpr int PH_ = H_ + 4;             // 52
constexpr int PHW_ = PH_ * PW_;         // 2704
constexpr int CHUNKS_ = HW_ / 256;      // 9 chunks of 64 quads per image

typedef float f32x4 __attribute__((ext_vector_type(4)));

// Kernel 1: padded channel-sum of frames: cs[img][52][52] (fp32), zero border.
__global__ void kcs(const float* __restrict__ frames, float* __restrict__ cs) {
    int id = blockIdx.x * blockDim.x + threadIdx.x;
    if (id >= IMGS_ * PHW_) return;
    int img = id / PHW_;
    int rem = id - img * PHW_;
    int ph = rem / PW_;
    int pw = rem - ph * PW_;
    int h = ph - 2, w = pw - 2;
    float s = 0.f;
    if ((unsigned)h < (unsigned)H_ && (unsigned)w < (unsigned)W_) {
        const float* f = frames + (size_t)img * (C_ * HW_) + h * W_ + w;
        s = f[0] + f[HW_] + f[2 * HW_];
    }
    cs[id] = s;
}

// Kernel 2: main fused conv, ONE CHANNEL PER BLOCK (grid = imgs*chunks*3).
// Block = 256 threads = 4 waves; wave g computes the partial
// kw[g,c] * sum_k core[g*75+k*3+c] * fs for 64 pixel-quads of channel c,
// then a 4-way LDS reduce over g.
// Rationale vs 481us version: 3x more blocks (13 queued/CU vs 4.5),
// per-thread chain shrinks from 75 loads/300 FMAs to 25 loads/100 FMAs ->
// much deeper memory-level parallelism for this purely-streaming kernel.
__global__ __launch_bounds__(256) void kmain(const float* __restrict__ core,
                                             const float* __restrict__ kw,
                                             const float* __restrict__ cs,
                                             float* __restrict__ out) {
    __shared__ float red[4][4][64];      // [g][j][q] = 4 KB

    int t = threadIdx.x;
    int q = t & 63;        // quad index within chunk
    int g = t >> 6;        // kernel-weight group = wave id
    int bx = blockIdx.x;
    int c = bx % 3;        // channel fastest: consecutive blocks stream
    int ic = bx / 3;       //   adjacent core planes (k*3+c interleave)
    int img = ic / CHUNKS_;
    int chunk = ic - img * CHUNKS_;
    int pix0 = chunk * 256 + q * 4;
    int h = pix0 / W_;
    int w0 = pix0 - h * W_;

    // 5x8 channel-sum tile (padded coords: rows h..h+4, cols w0..w0+7).
    // cs is 1.4 MB total -> the 3 channel-blocks per chunk re-read it from L2/L3.
    float fs[5][8];
    const float* csp = cs + img * PHW_ + h * PW_ + w0;
#pragma unroll
    for (int rr = 0; rr < 5; ++rr) {
        f32x4 a = *(const f32x4*)(csp + rr * PW_);
        f32x4 b = *(const f32x4*)(csp + rr * PW_ + 4);
        fs[rr][0] = a.x; fs[rr][1] = a.y; fs[rr][2] = a.z; fs[rr][3] = a.w;
        fs[rr][4] = b.x; fs[rr][5] = b.y; fs[rr][6] = b.z; fs[rr][7] = b.w;
    }

    // core plane (g*75 + k*3 + c), stream-once -> nontemporal (don't thrash L2).
    const float* cp = core + (size_t)img * (300 * HW_)
                           + (size_t)(g * 75 + c) * HW_ + pix0;

    float t0 = 0.f, t1 = 0.f, t2 = 0.f, t3 = 0.f;
#pragma unroll
    for (int k = 0; k < 25; ++k) {
        f32x4 d = __builtin_nontemporal_load((const f32x4*)(cp + (size_t)(k * 3) * HW_));
        int di = k / 5, dj = k - di * 5;
        t0 += d.x * fs[di][dj + 0];
        t1 += d.y * fs[di][dj + 1];
        t2 += d.z * fs[di][dj + 2];
        t3 += d.w * fs[di][dj + 3];
    }
    f32x4 kd = __builtin_nontemporal_load(
        (const f32x4*)(kw + (size_t)img * (12 * HW_) + (size_t)(g * 3 + c) * HW_ + pix0));
    red[g][0][q] = kd.x * t0;
    red[g][1][q] = kd.y * t1;
    red[g][2][q] = kd.z * t2;
    red[g][3][q] = kd.w * t3;

    __syncthreads();

    // 4-way reduce over g; threads 0..63, thread q' handles 4 pixels.
    if (t < 64) {
        f32x4 o;
#pragma unroll
        for (int j = 0; j < 4; ++j) {
            o[j] = 0.25f * (red[0][j][t] + red[1][j][t] + red[2][j][t] + red[3][j][t]);
        }
        *(f32x4*)(out + (size_t)img * (3 * HW_) + (size_t)c * HW_ + chunk * 256 + t * 4) = o;
    }
}

// Kernel 3: pred_img[b,c,h,w] = mean over n of pred_img_i
__global__ void kmean(const float* __restrict__ outi, float* __restrict__ outm) {
    int id = blockIdx.x * blockDim.x + threadIdx.x;
    if (id >= B_ * 3 * HW_) return;
    int b = id / (3 * HW_);
    int rem = id - b * (3 * HW_);
    const float* p = outi + (size_t)b * (N_ * 3 * HW_) + rem;
    float s = 0.f;
#pragma unroll
    for (int n = 0; n < N_; ++n) s += p[(size_t)n * 3 * HW_];
    outm[id] = s * 0.125f;
}

extern "C" void kernel_launch(void* const* d_in, const int* in_sizes, int n_in,
                              void* d_out, int out_size, void* d_ws, size_t ws_size,
                              hipStream_t stream) {
    const float* frames = (const float*)d_in[0];   // [B,N,3,H,W]
    const float* core = (const float*)d_in[1];     // [B,N,300,H,W] (flat middle dims)
    const float* kw = (const float*)d_in[2];       // [B,N,4,3,H,W]
    float* cs = (float*)d_ws;                      // 128*52*52 fp32 = 1.38 MB
    float* outi = (float*)d_out;                   // pred_img_i: [B,N,3,H,W]
    float* outm = outi + (size_t)B_ * N_ * 3 * HW_; // pred_img: [B,3,H,W]

    kcs<<<(IMGS_ * PHW_ + 255) / 256, 256, 0, stream>>>(frames, cs);
    kmain<<<IMGS_ * CHUNKS_ * 3, 256, 0, stream>>>(core, kw, cs, outi);
    kmean<<<(B_ * 3 * HW_ + 255) / 256, 256, 0, stream>>>(outi, outm);
}